// Round 2
// baseline (1596.678 us; speedup 1.0000x reference)
//
#include <hip/hip_runtime.h>

// RWKV block on MI355X (gfx950).  B=8, T=2048, C=1024, M=16384.
// Workspace budget: 176 MB (x2 residual stream lives in d_out; h split in halves).
//
// Pipeline:
//   1. transpose+cast W_tm/W_cm/W_cp -> bf16 B^T layout (ws)
//   2. LN1(x) -> xn (bf16)
//   3. GEMM1: xn @ W_tm (M x 3072), epilogue: mix with x_prev -> k,v,r (bf16)
//   4. WKV sequential scan -> x2 = x + r*y (f32, stored in d_out), state -> d_out tail
//   5. LN2(x2) -> xn (bf16) + rr = sigmoid(...) (bf16, overlays rb) + xp_s = bf16(shifted x2)
//   6. GEMM2 (x2 halves): xn @ W_cm[:,half] -> mix/relu^2 -> h_half (bf16, overlays kb+vb)
//   7. GEMM3 (x2 halves): h_half @ W_cp[half,:] -> out = x2 + rr*vv (pass0), out += (pass1)

#define Bb 8
#define T 2048
#define C 1024
#define M (Bb*T)
#define LDK 72   // padded LDS row stride in shorts (64 + 8) -> 2-way bank alias only (free, m136)

typedef unsigned short u16;
typedef unsigned int u32;
typedef __bf16 bf16x8 __attribute__((ext_vector_type(8)));
typedef float f32x4 __attribute__((ext_vector_type(4)));
typedef u16 u16x4 __attribute__((ext_vector_type(4)));

__device__ __forceinline__ u16 f2bf(float f) {
    u32 u = __float_as_uint(f);
    u32 r = u + 0x7FFFu + ((u >> 16) & 1u);   // round-to-nearest-even
    return (u16)(r >> 16);
}
__device__ __forceinline__ float bf2f(u16 s) {
    return __uint_as_float(((u32)s) << 16);
}
__device__ __forceinline__ float sigmoidf_(float z) {
    return 1.0f / (1.0f + __expf(-z));
}

// ---------------- weight transpose + cast: Wt[n][k] = bf16(W[k][n]) ----------------
__global__ __launch_bounds__(256) void transpose_cast_kernel(
    const float* __restrict__ W, u16* __restrict__ Wt, int K, int N)
{
    __shared__ float tile[32][33];
    const int bk = blockIdx.x * 32, bn = blockIdx.y * 32;
    const int tx = threadIdx.x, ty = threadIdx.y;   // (32,8)
    #pragma unroll
    for (int i = 0; i < 32; i += 8)
        tile[ty + i][tx] = W[(size_t)(bk + ty + i) * N + bn + tx];
    __syncthreads();
    #pragma unroll
    for (int i = 0; i < 32; i += 8)
        Wt[(size_t)(bn + ty + i) * K + bk + tx] = f2bf(tile[tx][ty + i]);
}

// ------------- GEMM mainloop: A (M x lda bf16 row-major), Bt (N x ldb bf16 row-major) -------------
__device__ __forceinline__ void gemm_mainloop(
    const u16* __restrict__ A, const int lda,
    const u16* __restrict__ Bt, const int ldb, const int K,
    const int m0, const int n0, u16* Alds, u16* Blds, f32x4 acc[4][4])
{
    const int tid  = threadIdx.x;
    const int wave = tid >> 6, lane = tid & 63;
    const int q = lane >> 4, m16 = lane & 15;
    const int wr = (wave >> 1) << 6, wc = (wave & 1) << 6;

    const f32x4 zero4 = {0.f, 0.f, 0.f, 0.f};
    #pragma unroll
    for (int i = 0; i < 4; i++)
        #pragma unroll
        for (int j = 0; j < 4; j++) acc[i][j] = zero4;

    const int r0 = tid >> 3;          // 0..31
    const int c8 = (tid & 7) * 8;     // 0..56, in shorts

    for (int k0 = 0; k0 < K; k0 += 64) {
        #pragma unroll
        for (int t = 0; t < 4; ++t) {
            const int row = r0 + t * 32;
            *(uint4*)&Alds[row * LDK + c8] =
                *(const uint4*)&A[(size_t)(m0 + row) * lda + k0 + c8];
            *(uint4*)&Blds[row * LDK + c8] =
                *(const uint4*)&Bt[(size_t)(n0 + row) * ldb + k0 + c8];
        }
        __syncthreads();
        #pragma unroll
        for (int s = 0; s < 2; ++s) {
            bf16x8 a[4], b[4];
            #pragma unroll
            for (int i = 0; i < 4; i++)
                a[i] = *(const bf16x8*)&Alds[(wr + i * 16 + m16) * LDK + s * 32 + q * 8];
            #pragma unroll
            for (int j = 0; j < 4; j++)
                b[j] = *(const bf16x8*)&Blds[(wc + j * 16 + m16) * LDK + s * 32 + q * 8];
            #pragma unroll
            for (int i = 0; i < 4; i++)
                #pragma unroll
                for (int j = 0; j < 4; j++)
                    acc[i][j] = __builtin_amdgcn_mfma_f32_16x16x32_bf16(a[i], b[j], acc[i][j], 0, 0, 0);
        }
        __syncthreads();
    }
}

// ---------------- LN1: xn = LN(x,g1,b1) as bf16 ----------------
__global__ __launch_bounds__(256) void ln1_kernel(
    const float* __restrict__ x, const float* __restrict__ g, const float* __restrict__ b,
    u16* __restrict__ xn)
{
    const int row = blockIdx.x, tid = threadIdx.x;
    const size_t base = (size_t)row * C;
    const int c = tid * 4;
    float4 v = *(const float4*)&x[base + c];
    float s  = v.x + v.y + v.z + v.w;
    float s2 = v.x*v.x + v.y*v.y + v.z*v.z + v.w*v.w;
    #pragma unroll
    for (int off = 32; off >= 1; off >>= 1) { s += __shfl_xor(s, off); s2 += __shfl_xor(s2, off); }
    __shared__ float red[8];
    const int wave = tid >> 6, lane = tid & 63;
    if (lane == 0) { red[wave] = s; red[4 + wave] = s2; }
    __syncthreads();
    const float sum  = red[0] + red[1] + red[2] + red[3];
    const float sums = red[4] + red[5] + red[6] + red[7];
    const float mean = sum * (1.0f / C);
    const float var  = sums * (1.0f / C) - mean * mean;
    const float rstd = rsqrtf(var + 1e-5f);
    float4 gv = *(const float4*)&g[c];
    float4 bv = *(const float4*)&b[c];
    u16x4 o;
    o.x = f2bf((v.x - mean) * rstd * gv.x + bv.x);
    o.y = f2bf((v.y - mean) * rstd * gv.y + bv.y);
    o.z = f2bf((v.z - mean) * rstd * gv.z + bv.z);
    o.w = f2bf((v.w - mean) * rstd * gv.w + bv.w);
    *(u16x4*)&xn[base + c] = o;
}

// ---------------- GEMM1 + k/v/r mixing epilogue (k,v,r stored bf16) ----------------
__global__ __launch_bounds__(256) void gemm1_kernel(
    const u16* __restrict__ xn, const u16* __restrict__ wt,
    const float* __restrict__ x,
    const float* __restrict__ tmk, const float* __restrict__ tmv, const float* __restrict__ tmr,
    u16* __restrict__ kbuf, u16* __restrict__ vbuf, u16* __restrict__ rbuf)
{
    __shared__ __align__(16) u16 Alds[128 * LDK];
    __shared__ __align__(16) u16 Blds[128 * LDK];
    f32x4 acc[4][4];
    const int m0 = blockIdx.x * 128, n0 = blockIdx.y * 128;
    gemm_mainloop(xn, C, wt, C, C, m0, n0, Alds, Blds, acc);

    const int tid = threadIdx.x, wave = tid >> 6, lane = tid & 63;
    const int q = lane >> 4, m16 = lane & 15;
    const int wr = (wave >> 1) << 6, wc = (wave & 1) << 6;
    const int grp = n0 >> 10;                  // 0=k, 1=v, 2=r (uniform per block)
    const int cbase = (n0 & 1023) + wc;
    #pragma unroll
    for (int i = 0; i < 4; i++) {
        #pragma unroll
        for (int rg = 0; rg < 4; rg++) {
            const int row = m0 + wr + i * 16 + q * 4 + rg;
            const int t = row & (T - 1);
            const size_t rowp = (size_t)(t ? row - 1 : row) * C;   // time-mix x_prev row
            #pragma unroll
            for (int j = 0; j < 4; j++) {
                const int cc = cbase + j * 16 + m16;
                const float val = acc[i][j][rg];
                const float xp = x[rowp + cc];
                if (grp == 0) {
                    const float f = tmk[cc];
                    kbuf[(size_t)row * C + cc] = f2bf(val * f + xp * (1.0f - f));
                } else if (grp == 1) {
                    const float f = tmv[cc];
                    vbuf[(size_t)row * C + cc] = f2bf(val * f + xp * (1.0f - f));
                } else {
                    const float f = tmr[cc];
                    rbuf[(size_t)row * C + cc] = f2bf(sigmoidf_(val * f + xp * (1.0f - f)));
                }
            }
        }
    }
}

// ---------------- WKV sequential scan + x2 = x + r*y (x2 -> d_out) ----------------
__global__ __launch_bounds__(64) void wkv_kernel(
    const u16* __restrict__ kbuf, const u16* __restrict__ vbuf,
    const u16* __restrict__ rbuf, const float* __restrict__ x,
    const float* __restrict__ wdec, const float* __restrict__ ufirst,
    float* __restrict__ x2, float* __restrict__ state)
{
    const int gid = blockIdx.x * 64 + threadIdx.x;   // 0..8191  (= b*C + c)
    const int cc = gid & (C - 1);
    const float w = wdec[cc], u = ufirst[cc];
    float aa = 0.0f, bb = -1e38f;
    size_t idx = (size_t)(gid >> 10) * T * C + cc;

    float kc = bf2f(kbuf[idx]), vc = bf2f(vbuf[idx]);
    float rc = bf2f(rbuf[idx]), xc = x[idx];
    for (int t = 0; t < T; ++t) {
        const size_t nidx = idx + C;
        float kn = 0.f, vn = 0.f, rn = 0.f, xnn = 0.f;
        if (t < T - 1) {   // uniform branch; prefetch next step
            kn = bf2f(kbuf[nidx]); vn = bf2f(vbuf[nidx]);
            rn = bf2f(rbuf[nidx]); xnn = x[nidx];
        }
        // y_t from old state
        float ww = u + kc;
        float p  = fmaxf(bb, ww);
        float e1 = __expf(bb - p), e2 = __expf(ww - p);
        const float y = (e1 * aa + e2 * vc) / (e1 + e2 + 1e-8f);
        // state update
        ww = w + bb;
        p  = fmaxf(ww, kc);
        e1 = __expf(ww - p); e2 = __expf(kc - p);
        aa = e1 * aa + e2 * vc;
        bb = p + __logf(e1 + e2 + 1e-8f);

        x2[idx] = xc + rc * y;
        idx = nidx; kc = kn; vc = vn; rc = rn; xc = xnn;
    }
    state[2 * gid]     = aa;
    state[2 * gid + 1] = bb;
}

// ---------------- LN2 + rr + xp_s snapshot ----------------
__global__ __launch_bounds__(256) void ln2_kernel(
    const float* __restrict__ x2, const float* __restrict__ g, const float* __restrict__ b,
    const float* __restrict__ cmr, u16* __restrict__ xn, u16* __restrict__ rr,
    u16* __restrict__ xps)
{
    const int row = blockIdx.x, tid = threadIdx.x;
    const size_t base = (size_t)row * C;
    const int t = row & (T - 1);
    const size_t basep = (size_t)(row - t + (t ? t - 1 : T - 1)) * C;   // cm xp row (wraps to last)
    const int c = tid * 4;
    float4 v = *(const float4*)&x2[base + c];
    float s  = v.x + v.y + v.z + v.w;
    float s2 = v.x*v.x + v.y*v.y + v.z*v.z + v.w*v.w;
    #pragma unroll
    for (int off = 32; off >= 1; off >>= 1) { s += __shfl_xor(s, off); s2 += __shfl_xor(s2, off); }
    __shared__ float red[8];
    const int wave = tid >> 6, lane = tid & 63;
    if (lane == 0) { red[wave] = s; red[4 + wave] = s2; }
    __syncthreads();
    const float sum  = red[0] + red[1] + red[2] + red[3];
    const float sums = red[4] + red[5] + red[6] + red[7];
    const float mean = sum * (1.0f / C);
    const float var  = sums * (1.0f / C) - mean * mean;
    const float rstd = rsqrtf(var + 1e-5f);
    float4 gv = *(const float4*)&g[c];
    float4 bv = *(const float4*)&b[c];
    float4 fv = *(const float4*)&cmr[c];
    float4 xp = *(const float4*)&x2[basep + c];
    float xn0 = (v.x - mean) * rstd * gv.x + bv.x;
    float xn1 = (v.y - mean) * rstd * gv.y + bv.y;
    float xn2 = (v.z - mean) * rstd * gv.z + bv.z;
    float xn3 = (v.w - mean) * rstd * gv.w + bv.w;
    u16x4 o; o.x = f2bf(xn0); o.y = f2bf(xn1); o.z = f2bf(xn2); o.w = f2bf(xn3);
    *(u16x4*)&xn[base + c] = o;
    u16x4 p4; p4.x = f2bf(xp.x); p4.y = f2bf(xp.y); p4.z = f2bf(xp.z); p4.w = f2bf(xp.w);
    *(u16x4*)&xps[base + c] = p4;
    u16x4 r4;
    r4.x = f2bf(sigmoidf_(xn0 * fv.x + xp.x * (1.0f - fv.x)));
    r4.y = f2bf(sigmoidf_(xn1 * fv.y + xp.y * (1.0f - fv.y)));
    r4.z = f2bf(sigmoidf_(xn2 * fv.z + xp.z * (1.0f - fv.z)));
    r4.w = f2bf(sigmoidf_(xn3 * fv.w + xp.w * (1.0f - fv.w)));
    *(u16x4*)&rr[base + c] = r4;
}

// ---------------- GEMM2 (one 2048-col half) + cm-mix + relu^2 -> h_half (bf16) ----------------
__global__ __launch_bounds__(256) void gemm2_kernel(
    const u16* __restrict__ xn, const u16* __restrict__ wt,   // wt pre-offset to half
    const u16* __restrict__ xps, const float* __restrict__ cmk,
    u16* __restrict__ hbuf, const int nbase)
{
    __shared__ __align__(16) u16 Alds[128 * LDK];
    __shared__ __align__(16) u16 Blds[128 * LDK];
    f32x4 acc[4][4];
    const int m0 = blockIdx.x * 128, n0 = blockIdx.y * 128;
    gemm_mainloop(xn, C, wt, C, C, m0, n0, Alds, Blds, acc);

    const int tid = threadIdx.x, wave = tid >> 6, lane = tid & 63;
    const int q = lane >> 4, m16 = lane & 15;
    const int wr = (wave >> 1) << 6, wc = (wave & 1) << 6;
    #pragma unroll
    for (int i = 0; i < 4; i++) {
        #pragma unroll
        for (int rg = 0; rg < 4; rg++) {
            const int row = m0 + wr + i * 16 + q * 4 + rg;
            #pragma unroll
            for (int j = 0; j < 4; j++) {
                const int nloc = n0 + wc + j * 16 + m16;         // 0..2047 within half
                const int cc = (nbase + nloc) & (C - 1);
                const float f = cmk[cc];
                const float xp = bf2f(xps[(size_t)row * C + cc]);
                const float kk = acc[i][j][rg] * f + xp * (1.0f - f);
                const float h = fmaxf(kk, 0.0f);
                hbuf[(size_t)row * 2048 + nloc] = f2bf(h * h);
            }
        }
    }
}

// ---------------- GEMM3 (K=2048 half) + residual epilogue, accumulate on pass 1 ----------------
__global__ __launch_bounds__(256) void gemm3_kernel(
    const u16* __restrict__ hbuf, const u16* __restrict__ wt,  // wt pre-offset to half
    const u16* __restrict__ rr, float* __restrict__ out, const int accumulate)
{
    __shared__ __align__(16) u16 Alds[128 * LDK];
    __shared__ __align__(16) u16 Blds[128 * LDK];
    f32x4 acc[4][4];
    const int m0 = blockIdx.x * 128, n0 = blockIdx.y * 128;
    gemm_mainloop(hbuf, 2048, wt, 4096, 2048, m0, n0, Alds, Blds, acc);

    const int tid = threadIdx.x, wave = tid >> 6, lane = tid & 63;
    const int q = lane >> 4, m16 = lane & 15;
    const int wr = (wave >> 1) << 6, wc = (wave & 1) << 6;
    #pragma unroll
    for (int i = 0; i < 4; i++) {
        #pragma unroll
        for (int rg = 0; rg < 4; rg++) {
            const int row = m0 + wr + i * 16 + q * 4 + rg;
            #pragma unroll
            for (int j = 0; j < 4; j++) {
                const int cc = n0 + wc + j * 16 + m16;
                const size_t idx = (size_t)row * C + cc;
                const float base = out[idx];   // pass0: x2; pass1: partial result
                out[idx] = base + bf2f(rr[idx]) * acc[i][j][rg];
            }
        }
    }
}

// ---------------- workspace layout (byte offsets), total 184,549,376 B = 176 MB ----------------
#define OFF_WT_CM  0            //  8 MB  (4096 x 1024 bf16)
#define OFF_WT_CP  8388608      //  8 MB  (1024 x 4096 bf16)
#define OFF_XN     16777216     // 32 MB  (M x C bf16; LN1 then LN2)
#define OFF_KB     50331648     // 32 MB  (bf16)
#define OFF_VB     83886080     // 32 MB  (bf16)
#define OFF_H      OFF_KB       // 64 MB  (M x 2048 bf16 half; overlays kb+vb, dead after wkv)
#define OFF_RB     117440512    // 32 MB  (bf16; reused as rr after wkv)
#define OFF_WT_TM  150994944    //  6 MB  (3072 x 1024 bf16; dead after gemm1)
#define OFF_XPS    150994944    // 32 MB  (bf16 shifted x2; overlays wt_tm, born at ln2)

extern "C" void kernel_launch(void* const* d_in, const int* in_sizes, int n_in,
                              void* d_out, int out_size, void* d_ws, size_t ws_size,
                              hipStream_t stream) {
    const float* x          = (const float*)d_in[0];
    const float* time_decay = (const float*)d_in[1];
    const float* time_first = (const float*)d_in[2];
    const float* W_tm       = (const float*)d_in[3];
    const float* g1         = (const float*)d_in[4];
    const float* b1         = (const float*)d_in[5];
    const float* tmk        = (const float*)d_in[6];
    const float* tmv        = (const float*)d_in[7];
    const float* tmr        = (const float*)d_in[8];
    const float* W_cm       = (const float*)d_in[9];
    const float* W_cp       = (const float*)d_in[10];
    const float* g2         = (const float*)d_in[11];
    const float* b2         = (const float*)d_in[12];
    const float* cmk        = (const float*)d_in[13];
    const float* cmr        = (const float*)d_in[14];
    float* out = (float*)d_out;

    char* ws = (char*)d_ws;
    u16*   wt_cm = (u16*)(ws + OFF_WT_CM);
    u16*   wt_cp = (u16*)(ws + OFF_WT_CP);
    u16*   xn    = (u16*)(ws + OFF_XN);
    u16*   kbuf  = (u16*)(ws + OFF_KB);
    u16*   vbuf  = (u16*)(ws + OFF_VB);
    u16*   hbuf  = (u16*)(ws + OFF_H);
    u16*   rbuf  = (u16*)(ws + OFF_RB);   // rr reuses this after wkv
    u16*   wt_tm = (u16*)(ws + OFF_WT_TM);
    u16*   xps   = (u16*)(ws + OFF_XPS);
    float* x2    = out;                    // residual stream lives in d_out

    // 1. weights -> bf16 B^T
    transpose_cast_kernel<<<dim3(1024/32, 3072/32), dim3(32, 8), 0, stream>>>(W_tm, wt_tm, 1024, 3072);
    transpose_cast_kernel<<<dim3(1024/32, 4096/32), dim3(32, 8), 0, stream>>>(W_cm, wt_cm, 1024, 4096);
    transpose_cast_kernel<<<dim3(4096/32, 1024/32), dim3(32, 8), 0, stream>>>(W_cp, wt_cp, 4096, 1024);
    // 2. LN1
    ln1_kernel<<<M, 256, 0, stream>>>(x, g1, b1, xn);
    // 3. GEMM1 + time-mix
    gemm1_kernel<<<dim3(M/128, 3072/128), 256, 0, stream>>>(xn, wt_tm, x, tmk, tmv, tmr,
                                                            kbuf, vbuf, rbuf);
    // 4. WKV scan (x2 -> d_out body, state -> d_out tail)
    wkv_kernel<<<dim3((Bb*C)/64), 64, 0, stream>>>(kbuf, vbuf, rbuf, x, time_decay, time_first,
                                                   x2, out + (size_t)M * C);
    // 5. LN2 + rr + xp snapshot
    ln2_kernel<<<M, 256, 0, stream>>>(x2, g2, b2, cmr, xn, rbuf, xps);
    // 6+7. channel-mix GEMMs in two hidden-halves (h_half overlays dead kb+vb)
    for (int half = 0; half < 2; ++half) {
        const int nbase = half * 2048;
        gemm2_kernel<<<dim3(M/128, 2048/128), 256, 0, stream>>>(
            xn, wt_cm + (size_t)nbase * C, xps, cmk, hbuf, nbase);
        gemm3_kernel<<<dim3(M/128, 1024/128), 256, 0, stream>>>(
            hbuf, wt_cp + nbase, rbuf, out, half);
    }
}

// Round 3
// 1294.126 us; speedup vs baseline: 1.2338x; 1.2338x over previous
//
#include <hip/hip_runtime.h>

// RWKV block on MI355X (gfx950).  B=8, T=2048, C=1024, M=16384.
// R2: (a) wkv 16-deep ring-buffer prefetch + packed (k,v) dword loads;
//     (b) GEMM staging via global_load_lds width=16 (m97 structure, unpadded LDS).
//
// Pipeline:
//   1. transpose+cast W_tm/W_cm/W_cp -> bf16 B^T layout (ws)
//   2. LN1(x) -> xn (bf16)
//   3. GEMM1: xn @ W_tm (M x 3072), epilogue: time-mix -> packed kv (bf16 pairs), r (bf16)
//   4. WKV sequential scan -> x2 = x + r*y (f32, in d_out), state -> d_out tail
//   5. LN2(x2) -> xn (bf16) + rr (bf16, overlays rb) + xp_s = bf16(shifted x2)
//   6. GEMM2 (halves): xn @ W_cm[:,half] -> mix/relu^2 -> h_half (bf16, overlays kv)
//   7. GEMM3 (halves): h_half @ W_cp[half,:] -> out = x2 + rr*vv (accumulating)

#define Bb 8
#define T 2048
#define C 1024
#define M (Bb*T)
#define WKV_D 16   // ring-buffer prefetch depth

typedef unsigned short u16;
typedef unsigned int u32;
typedef __bf16 bf16x8 __attribute__((ext_vector_type(8)));
typedef float f32x4 __attribute__((ext_vector_type(4)));
typedef u16 u16x4 __attribute__((ext_vector_type(4)));

__device__ __forceinline__ u16 f2bf(float f) {
    u32 u = __float_as_uint(f);
    u32 r = u + 0x7FFFu + ((u >> 16) & 1u);   // round-to-nearest-even
    return (u16)(r >> 16);
}
__device__ __forceinline__ float bf2f(u16 s) {
    return __uint_as_float(((u32)s) << 16);
}
__device__ __forceinline__ float sigmoidf_(float z) {
    return 1.0f / (1.0f + __expf(-z));
}
__device__ __forceinline__ void load_lds16(const void* g, void* l) {
    __builtin_amdgcn_global_load_lds(
        (const __attribute__((address_space(1))) void*)g,
        (__attribute__((address_space(3))) void*)l, 16, 0, 0);
}

// ---------------- weight transpose + cast: Wt[n][k] = bf16(W[k][n]) ----------------
__global__ __launch_bounds__(256) void transpose_cast_kernel(
    const float* __restrict__ W, u16* __restrict__ Wt, int K, int N)
{
    __shared__ float tile[32][33];
    const int bk = blockIdx.x * 32, bn = blockIdx.y * 32;
    const int tx = threadIdx.x, ty = threadIdx.y;   // (32,8)
    #pragma unroll
    for (int i = 0; i < 32; i += 8)
        tile[ty + i][tx] = W[(size_t)(bk + ty + i) * N + bn + tx];
    __syncthreads();
    #pragma unroll
    for (int i = 0; i < 32; i += 8)
        Wt[(size_t)(bn + ty + i) * K + bk + tx] = f2bf(tile[tx][ty + i]);
}

// ------------- GEMM mainloop (m97 structure): A (Mxlda), Bt (Nxldb), bf16 row-major -------------
// LDS tiles 128x64 shorts, unpadded (global_load_lds DMA: wave-uniform base + lane*16).
__device__ __forceinline__ void gemm_mainloop(
    const u16* __restrict__ A, const int lda,
    const u16* __restrict__ Bt, const int ldb, const int K,
    const int m0, const int n0, u16* Alds, u16* Blds, f32x4 acc[4][4])
{
    const int tid  = threadIdx.x;
    const int wave = tid >> 6, lane = tid & 63;
    const int q = lane >> 4, m16 = lane & 15;
    const int wr = (wave >> 1) << 6, wc = (wave & 1) << 6;

    const f32x4 zero4 = {0.f, 0.f, 0.f, 0.f};
    #pragma unroll
    for (int i = 0; i < 4; i++)
        #pragma unroll
        for (int j = 0; j < 4; j++) acc[i][j] = zero4;

    const int sr = tid >> 3;          // 0..31 (row within 32-row chunk)
    const int sc = (tid & 7) * 8;     // 0..56 shorts
    const u16* ag = &A[(size_t)(m0 + sr) * lda + sc];
    const u16* bg = &Bt[(size_t)(n0 + sr) * ldb + sc];
    u16* al = &Alds[tid * 8];         // LDS byte offset tid*16
    u16* bl = &Blds[tid * 8];

    for (int k0 = 0; k0 < K; k0 += 64) {
        #pragma unroll
        for (int t = 0; t < 4; ++t) {
            load_lds16(ag + (size_t)(t * 32) * lda + k0, al + t * 2048);
            load_lds16(bg + (size_t)(t * 32) * ldb + k0, bl + t * 2048);
        }
        __syncthreads();   // compiler drains vmcnt before s_barrier (m97 structure)
        #pragma unroll
        for (int s = 0; s < 2; ++s) {
            bf16x8 a[4], b[4];
            #pragma unroll
            for (int i = 0; i < 4; i++)
                a[i] = *(const bf16x8*)&Alds[(wr + i * 16 + m16) * 64 + s * 32 + q * 8];
            #pragma unroll
            for (int j = 0; j < 4; j++)
                b[j] = *(const bf16x8*)&Blds[(wc + j * 16 + m16) * 64 + s * 32 + q * 8];
            #pragma unroll
            for (int i = 0; i < 4; i++)
                #pragma unroll
                for (int j = 0; j < 4; j++)
                    acc[i][j] = __builtin_amdgcn_mfma_f32_16x16x32_bf16(a[i], b[j], acc[i][j], 0, 0, 0);
        }
        __syncthreads();
    }
}

// ---------------- LN1: xn = LN(x,g1,b1) as bf16 ----------------
__global__ __launch_bounds__(256) void ln1_kernel(
    const float* __restrict__ x, const float* __restrict__ g, const float* __restrict__ b,
    u16* __restrict__ xn)
{
    const int row = blockIdx.x, tid = threadIdx.x;
    const size_t base = (size_t)row * C;
    const int c = tid * 4;
    float4 v = *(const float4*)&x[base + c];
    float s  = v.x + v.y + v.z + v.w;
    float s2 = v.x*v.x + v.y*v.y + v.z*v.z + v.w*v.w;
    #pragma unroll
    for (int off = 32; off >= 1; off >>= 1) { s += __shfl_xor(s, off); s2 += __shfl_xor(s2, off); }
    __shared__ float red[8];
    const int wave = tid >> 6, lane = tid & 63;
    if (lane == 0) { red[wave] = s; red[4 + wave] = s2; }
    __syncthreads();
    const float sum  = red[0] + red[1] + red[2] + red[3];
    const float sums = red[4] + red[5] + red[6] + red[7];
    const float mean = sum * (1.0f / C);
    const float var  = sums * (1.0f / C) - mean * mean;
    const float rstd = rsqrtf(var + 1e-5f);
    float4 gv = *(const float4*)&g[c];
    float4 bv = *(const float4*)&b[c];
    u16x4 o;
    o.x = f2bf((v.x - mean) * rstd * gv.x + bv.x);
    o.y = f2bf((v.y - mean) * rstd * gv.y + bv.y);
    o.z = f2bf((v.z - mean) * rstd * gv.z + bv.z);
    o.w = f2bf((v.w - mean) * rstd * gv.w + bv.w);
    *(u16x4*)&xn[base + c] = o;
}

// ---------------- GEMM1 + time-mix epilogue -> packed kv (dword) + r (bf16) ----------------
__global__ __launch_bounds__(256) void gemm1_kernel(
    const u16* __restrict__ xn, const u16* __restrict__ wt,
    const float* __restrict__ x,
    const float* __restrict__ tmk, const float* __restrict__ tmv, const float* __restrict__ tmr,
    u16* __restrict__ kvbuf, u16* __restrict__ rbuf)
{
    __shared__ __align__(16) u16 Alds[128 * 64];
    __shared__ __align__(16) u16 Blds[128 * 64];
    f32x4 acc[4][4];
    const int m0 = blockIdx.x * 128, n0 = blockIdx.y * 128;
    gemm_mainloop(xn, C, wt, C, C, m0, n0, Alds, Blds, acc);

    const int tid = threadIdx.x, wave = tid >> 6, lane = tid & 63;
    const int q = lane >> 4, m16 = lane & 15;
    const int wr = (wave >> 1) << 6, wc = (wave & 1) << 6;
    const int grp = n0 >> 10;                  // 0=k, 1=v, 2=r (uniform per block)
    const int cbase = (n0 & 1023) + wc;
    #pragma unroll
    for (int i = 0; i < 4; i++) {
        #pragma unroll
        for (int rg = 0; rg < 4; rg++) {
            const int row = m0 + wr + i * 16 + q * 4 + rg;
            const int t = row & (T - 1);
            const size_t rowp = (size_t)(t ? row - 1 : row) * C;   // time-mix x_prev row
            #pragma unroll
            for (int j = 0; j < 4; j++) {
                const int cc = cbase + j * 16 + m16;
                const float val = acc[i][j][rg];
                const float xp = x[rowp + cc];
                if (grp == 0) {
                    const float f = tmk[cc];
                    kvbuf[(size_t)row * 2048 + 2 * cc] = f2bf(val * f + xp * (1.0f - f));
                } else if (grp == 1) {
                    const float f = tmv[cc];
                    kvbuf[(size_t)row * 2048 + 2 * cc + 1] = f2bf(val * f + xp * (1.0f - f));
                } else {
                    const float f = tmr[cc];
                    rbuf[(size_t)row * C + cc] = f2bf(sigmoidf_(val * f + xp * (1.0f - f)));
                }
            }
        }
    }
}

// ---------------- WKV scan: 16-deep ring-buffer prefetch ----------------
__device__ __forceinline__ void wkv_step(float kc, float vc, float rc, float xc,
                                         float w, float u, float& aa, float& bb,
                                         float* __restrict__ x2, size_t idx)
{
    float ww = u + kc;
    float p  = fmaxf(bb, ww);
    float e1 = __expf(bb - p), e2 = __expf(ww - p);
    const float y = (e1 * aa + e2 * vc) / (e1 + e2 + 1e-8f);
    ww = w + bb;
    p  = fmaxf(ww, kc);
    e1 = __expf(ww - p); e2 = __expf(kc - p);
    aa = e1 * aa + e2 * vc;
    bb = p + __logf(e1 + e2 + 1e-8f);
    x2[idx] = xc + rc * y;
}

__global__ __launch_bounds__(64) void wkv_kernel(
    const u32* __restrict__ kvp, const u16* __restrict__ rbuf,
    const float* __restrict__ x,
    const float* __restrict__ wdec, const float* __restrict__ ufirst,
    float* __restrict__ x2, float* __restrict__ state)
{
    const int gid = blockIdx.x * 64 + threadIdx.x;   // 0..8191 (= b*C + c)
    const int cc = gid & (C - 1);
    const float w = wdec[cc], u = ufirst[cc];
    float aa = 0.0f, bb = -1e38f;
    size_t L = (size_t)(gid >> 10) * T * C + cc;     // linear elem index, step C per t

    u32 kvq[WKV_D]; u16 rq[WKV_D]; float xq[WKV_D];
    #pragma unroll
    for (int d = 0; d < WKV_D; ++d) {
        const size_t Ld = L + (size_t)d * C;
        kvq[d] = kvp[Ld]; rq[d] = rbuf[Ld]; xq[d] = x[Ld];
    }
    for (int t0 = 0; t0 < T - WKV_D; t0 += WKV_D) {
        #pragma unroll
        for (int d = 0; d < WKV_D; ++d) {
            const u32 kv = kvq[d];
            const float rc = bf2f(rq[d]), xc = xq[d];
            const size_t Lp = L + (size_t)(d + WKV_D) * C;
            kvq[d] = kvp[Lp]; rq[d] = rbuf[Lp]; xq[d] = x[Lp];   // refill slot
            wkv_step(bf2f((u16)(kv & 0xffffu)), bf2f((u16)(kv >> 16)), rc, xc,
                     w, u, aa, bb, x2, L + (size_t)d * C);
        }
        L += (size_t)WKV_D * C;
    }
    #pragma unroll
    for (int d = 0; d < WKV_D; ++d) {                // tail block, no prefetch
        const u32 kv = kvq[d];
        wkv_step(bf2f((u16)(kv & 0xffffu)), bf2f((u16)(kv >> 16)), bf2f(rq[d]), xq[d],
                 w, u, aa, bb, x2, L + (size_t)d * C);
    }
    state[2 * gid]     = aa;
    state[2 * gid + 1] = bb;
}

// ---------------- LN2 + rr + xp_s snapshot ----------------
__global__ __launch_bounds__(256) void ln2_kernel(
    const float* __restrict__ x2, const float* __restrict__ g, const float* __restrict__ b,
    const float* __restrict__ cmr, u16* __restrict__ xn, u16* __restrict__ rr,
    u16* __restrict__ xps)
{
    const int row = blockIdx.x, tid = threadIdx.x;
    const size_t base = (size_t)row * C;
    const int t = row & (T - 1);
    const size_t basep = (size_t)(row - t + (t ? t - 1 : T - 1)) * C;   // cm xp row (wraps)
    const int c = tid * 4;
    float4 v = *(const float4*)&x2[base + c];
    float s  = v.x + v.y + v.z + v.w;
    float s2 = v.x*v.x + v.y*v.y + v.z*v.z + v.w*v.w;
    #pragma unroll
    for (int off = 32; off >= 1; off >>= 1) { s += __shfl_xor(s, off); s2 += __shfl_xor(s2, off); }
    __shared__ float red[8];
    const int wave = tid >> 6, lane = tid & 63;
    if (lane == 0) { red[wave] = s; red[4 + wave] = s2; }
    __syncthreads();
    const float sum  = red[0] + red[1] + red[2] + red[3];
    const float sums = red[4] + red[5] + red[6] + red[7];
    const float mean = sum * (1.0f / C);
    const float var  = sums * (1.0f / C) - mean * mean;
    const float rstd = rsqrtf(var + 1e-5f);
    float4 gv = *(const float4*)&g[c];
    float4 bv = *(const float4*)&b[c];
    float4 fv = *(const float4*)&cmr[c];
    float4 xp = *(const float4*)&x2[basep + c];
    float xn0 = (v.x - mean) * rstd * gv.x + bv.x;
    float xn1 = (v.y - mean) * rstd * gv.y + bv.y;
    float xn2 = (v.z - mean) * rstd * gv.z + bv.z;
    float xn3 = (v.w - mean) * rstd * gv.w + bv.w;
    u16x4 o; o.x = f2bf(xn0); o.y = f2bf(xn1); o.z = f2bf(xn2); o.w = f2bf(xn3);
    *(u16x4*)&xn[base + c] = o;
    u16x4 p4; p4.x = f2bf(xp.x); p4.y = f2bf(xp.y); p4.z = f2bf(xp.z); p4.w = f2bf(xp.w);
    *(u16x4*)&xps[base + c] = p4;
    u16x4 r4;
    r4.x = f2bf(sigmoidf_(xn0 * fv.x + xp.x * (1.0f - fv.x)));
    r4.y = f2bf(sigmoidf_(xn1 * fv.y + xp.y * (1.0f - fv.y)));
    r4.z = f2bf(sigmoidf_(xn2 * fv.z + xp.z * (1.0f - fv.z)));
    r4.w = f2bf(sigmoidf_(xn3 * fv.w + xp.w * (1.0f - fv.w)));
    *(u16x4*)&rr[base + c] = r4;
}

// ---------------- GEMM2 (one 2048-col half) + cm-mix + relu^2 -> h_half (bf16) ----------------
__global__ __launch_bounds__(256) void gemm2_kernel(
    const u16* __restrict__ xn, const u16* __restrict__ wt,   // wt pre-offset to half
    const u16* __restrict__ xps, const float* __restrict__ cmk,
    u16* __restrict__ hbuf, const int nbase)
{
    __shared__ __align__(16) u16 Alds[128 * 64];
    __shared__ __align__(16) u16 Blds[128 * 64];
    f32x4 acc[4][4];
    const int m0 = blockIdx.x * 128, n0 = blockIdx.y * 128;
    gemm_mainloop(xn, C, wt, C, C, m0, n0, Alds, Blds, acc);

    const int tid = threadIdx.x, wave = tid >> 6, lane = tid & 63;
    const int q = lane >> 4, m16 = lane & 15;
    const int wr = (wave >> 1) << 6, wc = (wave & 1) << 6;
    #pragma unroll
    for (int i = 0; i < 4; i++) {
        #pragma unroll
        for (int rg = 0; rg < 4; rg++) {
            const int row = m0 + wr + i * 16 + q * 4 + rg;
            #pragma unroll
            for (int j = 0; j < 4; j++) {
                const int nloc = n0 + wc + j * 16 + m16;         // 0..2047 within half
                const int cc = (nbase + nloc) & (C - 1);
                const float f = cmk[cc];
                const float xp = bf2f(xps[(size_t)row * C + cc]);
                const float kk = acc[i][j][rg] * f + xp * (1.0f - f);
                const float h = fmaxf(kk, 0.0f);
                hbuf[(size_t)row * 2048 + nloc] = f2bf(h * h);
            }
        }
    }
}

// ---------------- GEMM3 (K=2048 half) + residual epilogue, accumulates into out ----------------
__global__ __launch_bounds__(256) void gemm3_kernel(
    const u16* __restrict__ hbuf, const u16* __restrict__ wt,  // wt pre-offset to half
    const u16* __restrict__ rr, float* __restrict__ out)
{
    __shared__ __align__(16) u16 Alds[128 * 64];
    __shared__ __align__(16) u16 Blds[128 * 64];
    f32x4 acc[4][4];
    const int m0 = blockIdx.x * 128, n0 = blockIdx.y * 128;
    gemm_mainloop(hbuf, 2048, wt, 4096, 2048, m0, n0, Alds, Blds, acc);

    const int tid = threadIdx.x, wave = tid >> 6, lane = tid & 63;
    const int q = lane >> 4, m16 = lane & 15;
    const int wr = (wave >> 1) << 6, wc = (wave & 1) << 6;
    #pragma unroll
    for (int i = 0; i < 4; i++) {
        #pragma unroll
        for (int rg = 0; rg < 4; rg++) {
            const int row = m0 + wr + i * 16 + q * 4 + rg;
            #pragma unroll
            for (int j = 0; j < 4; j++) {
                const int cc = n0 + wc + j * 16 + m16;
                const size_t idx = (size_t)row * C + cc;
                const float base = out[idx];   // pass0: x2; pass1: partial result
                out[idx] = base + bf2f(rr[idx]) * acc[i][j][rg];
            }
        }
    }
}

// ---------------- workspace layout (byte offsets), total 176 MB ----------------
#define OFF_WT_CM  0            //  8 MB  (4096 x 1024 bf16)
#define OFF_WT_CP  8388608      //  8 MB  (1024 x 4096 bf16)
#define OFF_XN     16777216     // 32 MB  (M x C bf16; LN1 then LN2)
#define OFF_KV     50331648     // 64 MB  (M x C packed (k,v) bf16 pairs)
#define OFF_H      OFF_KV       // 64 MB  (M x 2048 bf16 half; overlays kv, dead after wkv)
#define OFF_RB     117440512    // 32 MB  (bf16; reused as rr after wkv)
#define OFF_WT_TM  150994944    //  6 MB  (3072 x 1024 bf16; dead after gemm1)
#define OFF_XPS    150994944    // 32 MB  (bf16 shifted x2; overlays wt_tm, born at ln2)

extern "C" void kernel_launch(void* const* d_in, const int* in_sizes, int n_in,
                              void* d_out, int out_size, void* d_ws, size_t ws_size,
                              hipStream_t stream) {
    const float* x          = (const float*)d_in[0];
    const float* time_decay = (const float*)d_in[1];
    const float* time_first = (const float*)d_in[2];
    const float* W_tm       = (const float*)d_in[3];
    const float* g1         = (const float*)d_in[4];
    const float* b1         = (const float*)d_in[5];
    const float* tmk        = (const float*)d_in[6];
    const float* tmv        = (const float*)d_in[7];
    const float* tmr        = (const float*)d_in[8];
    const float* W_cm       = (const float*)d_in[9];
    const float* W_cp       = (const float*)d_in[10];
    const float* g2         = (const float*)d_in[11];
    const float* b2         = (const float*)d_in[12];
    const float* cmk        = (const float*)d_in[13];
    const float* cmr        = (const float*)d_in[14];
    float* out = (float*)d_out;

    char* ws = (char*)d_ws;
    u16*   wt_cm = (u16*)(ws + OFF_WT_CM);
    u16*   wt_cp = (u16*)(ws + OFF_WT_CP);
    u16*   xn    = (u16*)(ws + OFF_XN);
    u16*   kvbuf = (u16*)(ws + OFF_KV);
    u16*   hbuf  = (u16*)(ws + OFF_H);
    u16*   rbuf  = (u16*)(ws + OFF_RB);   // rr reuses this after wkv
    u16*   wt_tm = (u16*)(ws + OFF_WT_TM);
    u16*   xps   = (u16*)(ws + OFF_XPS);
    float* x2    = out;                    // residual stream lives in d_out

    // 1. weights -> bf16 B^T
    transpose_cast_kernel<<<dim3(1024/32, 3072/32), dim3(32, 8), 0, stream>>>(W_tm, wt_tm, 1024, 3072);
    transpose_cast_kernel<<<dim3(1024/32, 4096/32), dim3(32, 8), 0, stream>>>(W_cm, wt_cm, 1024, 4096);
    transpose_cast_kernel<<<dim3(4096/32, 1024/32), dim3(32, 8), 0, stream>>>(W_cp, wt_cp, 4096, 1024);
    // 2. LN1
    ln1_kernel<<<M, 256, 0, stream>>>(x, g1, b1, xn);
    // 3. GEMM1 + time-mix
    gemm1_kernel<<<dim3(M/128, 3072/128), 256, 0, stream>>>(xn, wt_tm, x, tmk, tmv, tmr,
                                                            kvbuf, rbuf);
    // 4. WKV scan (x2 -> d_out body, state -> d_out tail)
    wkv_kernel<<<dim3((Bb*C)/64), 64, 0, stream>>>((const u32*)kvbuf, rbuf, x,
                                                   time_decay, time_first,
                                                   x2, out + (size_t)M * C);
    // 5. LN2 + rr + xp snapshot
    ln2_kernel<<<M, 256, 0, stream>>>(x2, g2, b2, cmr, xn, rbuf, xps);
    // 6+7. channel-mix GEMMs in two hidden-halves (h_half overlays dead kv)
    for (int half = 0; half < 2; ++half) {
        const int nbase = half * 2048;
        gemm2_kernel<<<dim3(M/128, 2048/128), 256, 0, stream>>>(
            xn, wt_cm + (size_t)nbase * C, xps, cmk, hbuf, nbase);
        gemm3_kernel<<<dim3(M/128, 1024/128), 256, 0, stream>>>(
            hbuf, wt_cp + nbase, rbuf, out);
    }
}

// Round 4
// 1075.692 us; speedup vs baseline: 1.4843x; 1.2031x over previous
//
#include <hip/hip_runtime.h>

// RWKV block on MI355X (gfx950).  B=8, T=2048, C=1024, M=16384.
// R3: WKV rewritten as chunked parallel scan (exact linear-map decomposition):
//   K1:  per-chunk local bc (bb with zero incoming state)      [parallel, 32 waves/CU]
//   P1:  log-space prefix over chunks -> bbin                  [tiny]
//   K2a: exact bb-trajectory given bbin -> (logS, R) per chunk [parallel]
//   P2:  prefix aain[j+1] = exp(logS_j)*aain[j] + R_j          [tiny]
//   K2c: exact replay with (aain,bbin): y, x2, final state     [parallel]
// GEMMs unchanged from R2 (m97-style global_load_lds staging).

#define Bb 8
#define T 2048
#define C 1024
#define M (Bb*T)
#define LCH 32            // chunk length
#define NCH 64            // chunks per sequence (T/LCH)
#define NCI (Bb*NCH)      // 512 chunk instances
#define WKV_THREADS (NCI*C)   // 524288

typedef unsigned short u16;
typedef unsigned int u32;
typedef __bf16 bf16x8 __attribute__((ext_vector_type(8)));
typedef float f32x4 __attribute__((ext_vector_type(4)));
typedef u16 u16x4 __attribute__((ext_vector_type(4)));

__device__ __forceinline__ u16 f2bf(float f) {
    u32 u = __float_as_uint(f);
    u32 r = u + 0x7FFFu + ((u >> 16) & 1u);   // round-to-nearest-even
    return (u16)(r >> 16);
}
__device__ __forceinline__ float bf2f(u16 s) {
    return __uint_as_float(((u32)s) << 16);
}
__device__ __forceinline__ float sigmoidf_(float z) {
    return 1.0f / (1.0f + __expf(-z));
}
__device__ __forceinline__ void load_lds16(const void* g, void* l) {
    __builtin_amdgcn_global_load_lds(
        (const __attribute__((address_space(1))) void*)g,
        (__attribute__((address_space(3))) void*)l, 16, 0, 0);
}

// ---------------- weight transpose + cast: Wt[n][k] = bf16(W[k][n]) ----------------
__global__ __launch_bounds__(256) void transpose_cast_kernel(
    const float* __restrict__ W, u16* __restrict__ Wt, int K, int N)
{
    __shared__ float tile[32][33];
    const int bk = blockIdx.x * 32, bn = blockIdx.y * 32;
    const int tx = threadIdx.x, ty = threadIdx.y;   // (32,8)
    #pragma unroll
    for (int i = 0; i < 32; i += 8)
        tile[ty + i][tx] = W[(size_t)(bk + ty + i) * N + bn + tx];
    __syncthreads();
    #pragma unroll
    for (int i = 0; i < 32; i += 8)
        Wt[(size_t)(bn + ty + i) * K + bk + tx] = f2bf(tile[tx][ty + i]);
}

// ------------- GEMM mainloop (m97 structure): A (Mxlda), Bt (Nxldb), bf16 row-major -------------
__device__ __forceinline__ void gemm_mainloop(
    const u16* __restrict__ A, const int lda,
    const u16* __restrict__ Bt, const int ldb, const int K,
    const int m0, const int n0, u16* Alds, u16* Blds, f32x4 acc[4][4])
{
    const int tid  = threadIdx.x;
    const int wave = tid >> 6, lane = tid & 63;
    const int q = lane >> 4, m16 = lane & 15;
    const int wr = (wave >> 1) << 6, wc = (wave & 1) << 6;

    const f32x4 zero4 = {0.f, 0.f, 0.f, 0.f};
    #pragma unroll
    for (int i = 0; i < 4; i++)
        #pragma unroll
        for (int j = 0; j < 4; j++) acc[i][j] = zero4;

    const int sr = tid >> 3;          // 0..31 (row within 32-row chunk)
    const int sc = (tid & 7) * 8;     // 0..56 shorts
    const u16* ag = &A[(size_t)(m0 + sr) * lda + sc];
    const u16* bg = &Bt[(size_t)(n0 + sr) * ldb + sc];
    u16* al = &Alds[tid * 8];         // LDS byte offset tid*16
    u16* bl = &Blds[tid * 8];

    for (int k0 = 0; k0 < K; k0 += 64) {
        #pragma unroll
        for (int t = 0; t < 4; ++t) {
            load_lds16(ag + (size_t)(t * 32) * lda + k0, al + t * 2048);
            load_lds16(bg + (size_t)(t * 32) * ldb + k0, bl + t * 2048);
        }
        __syncthreads();
        #pragma unroll
        for (int s = 0; s < 2; ++s) {
            bf16x8 a[4], b[4];
            #pragma unroll
            for (int i = 0; i < 4; i++)
                a[i] = *(const bf16x8*)&Alds[(wr + i * 16 + m16) * 64 + s * 32 + q * 8];
            #pragma unroll
            for (int j = 0; j < 4; j++)
                b[j] = *(const bf16x8*)&Blds[(wc + j * 16 + m16) * 64 + s * 32 + q * 8];
            #pragma unroll
            for (int i = 0; i < 4; i++)
                #pragma unroll
                for (int j = 0; j < 4; j++)
                    acc[i][j] = __builtin_amdgcn_mfma_f32_16x16x32_bf16(a[i], b[j], acc[i][j], 0, 0, 0);
        }
        __syncthreads();
    }
}

// ---------------- LN1: xn = LN(x,g1,b1) as bf16 ----------------
__global__ __launch_bounds__(256) void ln1_kernel(
    const float* __restrict__ x, const float* __restrict__ g, const float* __restrict__ b,
    u16* __restrict__ xn)
{
    const int row = blockIdx.x, tid = threadIdx.x;
    const size_t base = (size_t)row * C;
    const int c = tid * 4;
    float4 v = *(const float4*)&x[base + c];
    float s  = v.x + v.y + v.z + v.w;
    float s2 = v.x*v.x + v.y*v.y + v.z*v.z + v.w*v.w;
    #pragma unroll
    for (int off = 32; off >= 1; off >>= 1) { s += __shfl_xor(s, off); s2 += __shfl_xor(s2, off); }
    __shared__ float red[8];
    const int wave = tid >> 6, lane = tid & 63;
    if (lane == 0) { red[wave] = s; red[4 + wave] = s2; }
    __syncthreads();
    const float sum  = red[0] + red[1] + red[2] + red[3];
    const float sums = red[4] + red[5] + red[6] + red[7];
    const float mean = sum * (1.0f / C);
    const float var  = sums * (1.0f / C) - mean * mean;
    const float rstd = rsqrtf(var + 1e-5f);
    float4 gv = *(const float4*)&g[c];
    float4 bv = *(const float4*)&b[c];
    u16x4 o;
    o.x = f2bf((v.x - mean) * rstd * gv.x + bv.x);
    o.y = f2bf((v.y - mean) * rstd * gv.y + bv.y);
    o.z = f2bf((v.z - mean) * rstd * gv.z + bv.z);
    o.w = f2bf((v.w - mean) * rstd * gv.w + bv.w);
    *(u16x4*)&xn[base + c] = o;
}

// ---------------- GEMM1 + time-mix epilogue -> packed kv (dword) + r (bf16) ----------------
__global__ __launch_bounds__(256) void gemm1_kernel(
    const u16* __restrict__ xn, const u16* __restrict__ wt,
    const float* __restrict__ x,
    const float* __restrict__ tmk, const float* __restrict__ tmv, const float* __restrict__ tmr,
    u16* __restrict__ kvbuf, u16* __restrict__ rbuf)
{
    __shared__ __align__(16) u16 Alds[128 * 64];
    __shared__ __align__(16) u16 Blds[128 * 64];
    f32x4 acc[4][4];
    const int m0 = blockIdx.x * 128, n0 = blockIdx.y * 128;
    gemm_mainloop(xn, C, wt, C, C, m0, n0, Alds, Blds, acc);

    const int tid = threadIdx.x, wave = tid >> 6, lane = tid & 63;
    const int q = lane >> 4, m16 = lane & 15;
    const int wr = (wave >> 1) << 6, wc = (wave & 1) << 6;
    const int grp = n0 >> 10;                  // 0=k, 1=v, 2=r (uniform per block)
    const int cbase = (n0 & 1023) + wc;
    #pragma unroll
    for (int i = 0; i < 4; i++) {
        #pragma unroll
        for (int rg = 0; rg < 4; rg++) {
            const int row = m0 + wr + i * 16 + q * 4 + rg;
            const int t = row & (T - 1);
            const size_t rowp = (size_t)(t ? row - 1 : row) * C;   // time-mix x_prev row
            #pragma unroll
            for (int j = 0; j < 4; j++) {
                const int cc = cbase + j * 16 + m16;
                const float val = acc[i][j][rg];
                const float xp = x[rowp + cc];
                if (grp == 0) {
                    const float f = tmk[cc];
                    kvbuf[(size_t)row * 2048 + 2 * cc] = f2bf(val * f + xp * (1.0f - f));
                } else if (grp == 1) {
                    const float f = tmv[cc];
                    kvbuf[(size_t)row * 2048 + 2 * cc + 1] = f2bf(val * f + xp * (1.0f - f));
                } else {
                    const float f = tmr[cc];
                    rbuf[(size_t)row * C + cc] = f2bf(sigmoidf_(val * f + xp * (1.0f - f)));
                }
            }
        }
    }
}

// ================= WKV chunked parallel scan =================
// thread id -> c = tid & 1023, ci = tid >> 10 (chunk instance), b = ci>>6, j = ci&63.
// elem base = (b*T + j*LCH)*C + c.  Scratch arrays indexed [ci*C + c] = tid.

__global__ __launch_bounds__(256) void wkv_k1(
    const u32* __restrict__ kvp, const float* __restrict__ wdec, float* __restrict__ bc)
{
    const int tid = blockIdx.x * 256 + threadIdx.x;
    const int c = tid & (C - 1), ci = tid >> 10;
    const float w = wdec[c];
    const size_t L = ((size_t)(ci >> 6) * T + (size_t)(ci & (NCH - 1)) * LCH) * C + c;
    float bb = -1e38f;
    #pragma unroll 4
    for (int t = 0; t < LCH; ++t) {
        const float k = bf2f((u16)(kvp[L + (size_t)t * C] & 0xffffu));
        const float ww = w + bb;
        const float p = fmaxf(ww, k);
        const float e1 = __expf(ww - p), e2 = __expf(k - p);
        bb = p + __logf(e1 + e2 + 1e-8f);
    }
    bc[tid] = bb;
}

__global__ __launch_bounds__(256) void wkv_p1(
    const float* __restrict__ bc, const float* __restrict__ wdec, float* __restrict__ bbin)
{
    const int gid = blockIdx.x * 256 + threadIdx.x;   // 0..8191 = b*C + c
    const int c = gid & (C - 1), b = gid >> 10;
    const float Lw = (float)LCH * wdec[c];
    float bb = -1e38f;
    #pragma unroll 8
    for (int j = 0; j < NCH; ++j) {
        const int idx = (b * NCH + j) * C + c;
        bbin[idx] = bb;
        const float a = Lw + bb;
        const float bcv = bc[idx];
        const float m = fmaxf(a, bcv);
        bb = m + __logf(__expf(a - m) + __expf(bcv - m));
    }
}

__global__ __launch_bounds__(256) void wkv_k2a(
    const u32* __restrict__ kvp, const float* __restrict__ wdec,
    const float* __restrict__ bbin, float* __restrict__ logS, float* __restrict__ Rr)
{
    const int tid = blockIdx.x * 256 + threadIdx.x;
    const int c = tid & (C - 1), ci = tid >> 10;
    const float w = wdec[c];
    const size_t L = ((size_t)(ci >> 6) * T + (size_t)(ci & (NCH - 1)) * LCH) * C + c;
    float bb = bbin[tid], ls = 0.0f, R = 0.0f;
    #pragma unroll 4
    for (int t = 0; t < LCH; ++t) {
        const u32 kv = kvp[L + (size_t)t * C];
        const float k = bf2f((u16)(kv & 0xffffu)), v = bf2f((u16)(kv >> 16));
        const float ww = w + bb;
        const float p = fmaxf(ww, k);
        const float e1 = __expf(ww - p), e2 = __expf(k - p);
        R = e1 * R + e2 * v;
        ls += ww - p;                       // log of alpha product (<=0)
        bb = p + __logf(e1 + e2 + 1e-8f);
    }
    logS[tid] = ls;
    Rr[tid] = R;
}

__global__ __launch_bounds__(256) void wkv_p2(
    const float* __restrict__ logS, const float* __restrict__ Rr, float* __restrict__ aain)
{
    const int gid = blockIdx.x * 256 + threadIdx.x;   // b*C + c
    const int c = gid & (C - 1), b = gid >> 10;
    float a = 0.0f;
    #pragma unroll 8
    for (int j = 0; j < NCH; ++j) {
        const int idx = (b * NCH + j) * C + c;
        aain[idx] = a;
        a = __expf(logS[idx]) * a + Rr[idx];
    }
}

__global__ __launch_bounds__(256) void wkv_k2c(
    const u32* __restrict__ kvp, const u16* __restrict__ rbuf, const float* __restrict__ x,
    const float* __restrict__ wdec, const float* __restrict__ ufirst,
    const float* __restrict__ bbin, const float* __restrict__ aain,
    float* __restrict__ x2, float* __restrict__ state)
{
    const int tid = blockIdx.x * 256 + threadIdx.x;
    const int c = tid & (C - 1), ci = tid >> 10;
    const int b = ci >> 6, j = ci & (NCH - 1);
    const float w = wdec[c], u = ufirst[c];
    float aa = aain[tid], bb = bbin[tid];
    const size_t L = ((size_t)b * T + (size_t)j * LCH) * C + c;
    #pragma unroll 4
    for (int t = 0; t < LCH; ++t) {
        const size_t idx = L + (size_t)t * C;
        const u32 kv = kvp[idx];
        const float k = bf2f((u16)(kv & 0xffffu)), v = bf2f((u16)(kv >> 16));
        const float r = bf2f(rbuf[idx]), xv = x[idx];
        float ww = u + k;
        float p  = fmaxf(bb, ww);
        float e1 = __expf(bb - p), e2 = __expf(ww - p);
        const float y = (e1 * aa + e2 * v) / (e1 + e2 + 1e-8f);
        x2[idx] = xv + r * y;
        ww = w + bb;
        p  = fmaxf(ww, k);
        e1 = __expf(ww - p); e2 = __expf(k - p);
        aa = e1 * aa + e2 * v;
        bb = p + __logf(e1 + e2 + 1e-8f);
    }
    if (j == NCH - 1) {
        state[2 * (b * C + c)]     = aa;
        state[2 * (b * C + c) + 1] = bb;
    }
}

// ---------------- LN2 + rr + xp_s snapshot ----------------
__global__ __launch_bounds__(256) void ln2_kernel(
    const float* __restrict__ x2, const float* __restrict__ g, const float* __restrict__ b,
    const float* __restrict__ cmr, u16* __restrict__ xn, u16* __restrict__ rr,
    u16* __restrict__ xps)
{
    const int row = blockIdx.x, tid = threadIdx.x;
    const size_t base = (size_t)row * C;
    const int t = row & (T - 1);
    const size_t basep = (size_t)(row - t + (t ? t - 1 : T - 1)) * C;   // cm xp row (wraps)
    const int c = tid * 4;
    float4 v = *(const float4*)&x2[base + c];
    float s  = v.x + v.y + v.z + v.w;
    float s2 = v.x*v.x + v.y*v.y + v.z*v.z + v.w*v.w;
    #pragma unroll
    for (int off = 32; off >= 1; off >>= 1) { s += __shfl_xor(s, off); s2 += __shfl_xor(s2, off); }
    __shared__ float red[8];
    const int wave = tid >> 6, lane = tid & 63;
    if (lane == 0) { red[wave] = s; red[4 + wave] = s2; }
    __syncthreads();
    const float sum  = red[0] + red[1] + red[2] + red[3];
    const float sums = red[4] + red[5] + red[6] + red[7];
    const float mean = sum * (1.0f / C);
    const float var  = sums * (1.0f / C) - mean * mean;
    const float rstd = rsqrtf(var + 1e-5f);
    float4 gv = *(const float4*)&g[c];
    float4 bv = *(const float4*)&b[c];
    float4 fv = *(const float4*)&cmr[c];
    float4 xp = *(const float4*)&x2[basep + c];
    float xn0 = (v.x - mean) * rstd * gv.x + bv.x;
    float xn1 = (v.y - mean) * rstd * gv.y + bv.y;
    float xn2 = (v.z - mean) * rstd * gv.z + bv.z;
    float xn3 = (v.w - mean) * rstd * gv.w + bv.w;
    u16x4 o; o.x = f2bf(xn0); o.y = f2bf(xn1); o.z = f2bf(xn2); o.w = f2bf(xn3);
    *(u16x4*)&xn[base + c] = o;
    u16x4 p4; p4.x = f2bf(xp.x); p4.y = f2bf(xp.y); p4.z = f2bf(xp.z); p4.w = f2bf(xp.w);
    *(u16x4*)&xps[base + c] = p4;
    u16x4 r4;
    r4.x = f2bf(sigmoidf_(xn0 * fv.x + xp.x * (1.0f - fv.x)));
    r4.y = f2bf(sigmoidf_(xn1 * fv.y + xp.y * (1.0f - fv.y)));
    r4.z = f2bf(sigmoidf_(xn2 * fv.z + xp.z * (1.0f - fv.z)));
    r4.w = f2bf(sigmoidf_(xn3 * fv.w + xp.w * (1.0f - fv.w)));
    *(u16x4*)&rr[base + c] = r4;
}

// ---------------- GEMM2 (one 2048-col half) + cm-mix + relu^2 -> h_half (bf16) ----------------
__global__ __launch_bounds__(256) void gemm2_kernel(
    const u16* __restrict__ xn, const u16* __restrict__ wt,   // wt pre-offset to half
    const u16* __restrict__ xps, const float* __restrict__ cmk,
    u16* __restrict__ hbuf, const int nbase)
{
    __shared__ __align__(16) u16 Alds[128 * 64];
    __shared__ __align__(16) u16 Blds[128 * 64];
    f32x4 acc[4][4];
    const int m0 = blockIdx.x * 128, n0 = blockIdx.y * 128;
    gemm_mainloop(xn, C, wt, C, C, m0, n0, Alds, Blds, acc);

    const int tid = threadIdx.x, wave = tid >> 6, lane = tid & 63;
    const int q = lane >> 4, m16 = lane & 15;
    const int wr = (wave >> 1) << 6, wc = (wave & 1) << 6;
    #pragma unroll
    for (int i = 0; i < 4; i++) {
        #pragma unroll
        for (int rg = 0; rg < 4; rg++) {
            const int row = m0 + wr + i * 16 + q * 4 + rg;
            #pragma unroll
            for (int j = 0; j < 4; j++) {
                const int nloc = n0 + wc + j * 16 + m16;         // 0..2047 within half
                const int cc = (nbase + nloc) & (C - 1);
                const float f = cmk[cc];
                const float xp = bf2f(xps[(size_t)row * C + cc]);
                const float kk = acc[i][j][rg] * f + xp * (1.0f - f);
                const float h = fmaxf(kk, 0.0f);
                hbuf[(size_t)row * 2048 + nloc] = f2bf(h * h);
            }
        }
    }
}

// ---------------- GEMM3 (K=2048 half) + residual epilogue, accumulates into out ----------------
__global__ __launch_bounds__(256) void gemm3_kernel(
    const u16* __restrict__ hbuf, const u16* __restrict__ wt,  // wt pre-offset to half
    const u16* __restrict__ rr, float* __restrict__ out)
{
    __shared__ __align__(16) u16 Alds[128 * 64];
    __shared__ __align__(16) u16 Blds[128 * 64];
    f32x4 acc[4][4];
    const int m0 = blockIdx.x * 128, n0 = blockIdx.y * 128;
    gemm_mainloop(hbuf, 2048, wt, 4096, 2048, m0, n0, Alds, Blds, acc);

    const int tid = threadIdx.x, wave = tid >> 6, lane = tid & 63;
    const int q = lane >> 4, m16 = lane & 15;
    const int wr = (wave >> 1) << 6, wc = (wave & 1) << 6;
    #pragma unroll
    for (int i = 0; i < 4; i++) {
        #pragma unroll
        for (int rg = 0; rg < 4; rg++) {
            const int row = m0 + wr + i * 16 + q * 4 + rg;
            #pragma unroll
            for (int j = 0; j < 4; j++) {
                const int cc = n0 + wc + j * 16 + m16;
                const size_t idx = (size_t)row * C + cc;
                const float base = out[idx];   // pass0: x2; pass1: partial result
                out[idx] = base + bf2f(rr[idx]) * acc[i][j][rg];
            }
        }
    }
}

// ---------------- workspace layout (byte offsets), total 176 MB ----------------
#define OFF_WT_CM  0            //  8 MB  (4096 x 1024 bf16)
#define OFF_WT_CP  8388608      //  8 MB  (1024 x 4096 bf16)
#define OFF_XN     16777216     // 32 MB  (M x C bf16; LN1 then LN2)
#define OFF_KV     50331648     // 64 MB  (M x C packed (k,v) bf16 pairs)
#define OFF_H      OFF_KV       // 64 MB  (M x 2048 bf16 half; overlays kv, dead after wkv)
#define OFF_RB     117440512    // 32 MB  (bf16; reused as rr after wkv)
#define OFF_WT_TM  150994944    //  6 MB  (3072 x 1024 bf16; dead after gemm1)
// wkv scratch overlays the wt_tm/xps extent during the scan (dead then):
#define OFF_BC     150994944    // 2 MB
#define OFF_BBIN   153092096    // 2 MB
#define OFF_LOGS   155189248    // 2 MB
#define OFF_RCH    157286400    // 2 MB
#define OFF_AAIN   159383552    // 2 MB
#define OFF_XPS    150994944    // 32 MB (bf16 shifted x2; born at ln2, after wkv)

extern "C" void kernel_launch(void* const* d_in, const int* in_sizes, int n_in,
                              void* d_out, int out_size, void* d_ws, size_t ws_size,
                              hipStream_t stream) {
    const float* x          = (const float*)d_in[0];
    const float* time_decay = (const float*)d_in[1];
    const float* time_first = (const float*)d_in[2];
    const float* W_tm       = (const float*)d_in[3];
    const float* g1         = (const float*)d_in[4];
    const float* b1         = (const float*)d_in[5];
    const float* tmk        = (const float*)d_in[6];
    const float* tmv        = (const float*)d_in[7];
    const float* tmr        = (const float*)d_in[8];
    const float* W_cm       = (const float*)d_in[9];
    const float* W_cp       = (const float*)d_in[10];
    const float* g2         = (const float*)d_in[11];
    const float* b2         = (const float*)d_in[12];
    const float* cmk        = (const float*)d_in[13];
    const float* cmr        = (const float*)d_in[14];
    float* out = (float*)d_out;

    char* ws = (char*)d_ws;
    u16*   wt_cm = (u16*)(ws + OFF_WT_CM);
    u16*   wt_cp = (u16*)(ws + OFF_WT_CP);
    u16*   xn    = (u16*)(ws + OFF_XN);
    u16*   kvbuf = (u16*)(ws + OFF_KV);
    u16*   hbuf  = (u16*)(ws + OFF_H);
    u16*   rbuf  = (u16*)(ws + OFF_RB);   // rr reuses this after wkv
    u16*   wt_tm = (u16*)(ws + OFF_WT_TM);
    u16*   xps   = (u16*)(ws + OFF_XPS);
    float* bc    = (float*)(ws + OFF_BC);
    float* bbin  = (float*)(ws + OFF_BBIN);
    float* logS  = (float*)(ws + OFF_LOGS);
    float* Rch   = (float*)(ws + OFF_RCH);
    float* aain  = (float*)(ws + OFF_AAIN);
    float* x2    = out;                    // residual stream lives in d_out

    // 1. weights -> bf16 B^T
    transpose_cast_kernel<<<dim3(1024/32, 3072/32), dim3(32, 8), 0, stream>>>(W_tm, wt_tm, 1024, 3072);
    transpose_cast_kernel<<<dim3(1024/32, 4096/32), dim3(32, 8), 0, stream>>>(W_cm, wt_cm, 1024, 4096);
    transpose_cast_kernel<<<dim3(4096/32, 1024/32), dim3(32, 8), 0, stream>>>(W_cp, wt_cp, 4096, 1024);
    // 2. LN1
    ln1_kernel<<<M, 256, 0, stream>>>(x, g1, b1, xn);
    // 3. GEMM1 + time-mix
    gemm1_kernel<<<dim3(M/128, 3072/128), 256, 0, stream>>>(xn, wt_tm, x, tmk, tmv, tmr,
                                                            kvbuf, rbuf);
    // 4. WKV chunked parallel scan (x2 -> d_out body, state -> d_out tail)
    {
        const u32* kvp = (const u32*)kvbuf;
        wkv_k1 <<<WKV_THREADS/256, 256, 0, stream>>>(kvp, time_decay, bc);
        wkv_p1 <<<(Bb*C)/256, 256, 0, stream>>>(bc, time_decay, bbin);
        wkv_k2a<<<WKV_THREADS/256, 256, 0, stream>>>(kvp, time_decay, bbin, logS, Rch);
        wkv_p2 <<<(Bb*C)/256, 256, 0, stream>>>(logS, Rch, aain);
        wkv_k2c<<<WKV_THREADS/256, 256, 0, stream>>>(kvp, rbuf, x, time_decay, time_first,
                                                     bbin, aain, x2, out + (size_t)M * C);
    }
    // 5. LN2 + rr + xp snapshot
    ln2_kernel<<<M, 256, 0, stream>>>(x2, g2, b2, cmr, xn, rbuf, xps);
    // 6+7. channel-mix GEMMs in two hidden-halves (h_half overlays dead kv)
    for (int half = 0; half < 2; ++half) {
        const int nbase = half * 2048;
        gemm2_kernel<<<dim3(M/128, 2048/128), 256, 0, stream>>>(
            xn, wt_cm + (size_t)nbase * C, xps, cmk, hbuf, nbase);
        gemm3_kernel<<<dim3(M/128, 1024/128), 256, 0, stream>>>(
            hbuf, wt_cp + nbase, rbuf, out);
    }
}

// Round 5
// 937.887 us; speedup vs baseline: 1.7024x; 1.1469x over previous
//
#include <hip/hip_runtime.h>

// RWKV block on MI355X (gfx950).  B=8, T=2048, C=1024, M=16384.
// R4: XOR-swizzled LDS layout in the GEMM mainloop to kill the 3.8e7 bank
//     conflicts/dispatch (unpadded 128B row stride put 16 lanes on one 4-bank
//     group).  LDS row r chunk c now holds global chunk c^(r&7); the staging
//     DMA achieves this by swizzling the *source* column (dst is fixed
//     lane*16), and the fragment read XORs the chunk index with m16&7.
// WKV: chunked parallel scan (R3).  Everything else unchanged.

#define Bb 8
#define T 2048
#define C 1024
#define M (Bb*T)
#define LCH 32            // chunk length
#define NCH 64            // chunks per sequence (T/LCH)
#define NCI (Bb*NCH)      // 512 chunk instances
#define WKV_THREADS (NCI*C)   // 524288

typedef unsigned short u16;
typedef unsigned int u32;
typedef __bf16 bf16x8 __attribute__((ext_vector_type(8)));
typedef float f32x4 __attribute__((ext_vector_type(4)));
typedef u16 u16x4 __attribute__((ext_vector_type(4)));

__device__ __forceinline__ u16 f2bf(float f) {
    u32 u = __float_as_uint(f);
    u32 r = u + 0x7FFFu + ((u >> 16) & 1u);   // round-to-nearest-even
    return (u16)(r >> 16);
}
__device__ __forceinline__ float bf2f(u16 s) {
    return __uint_as_float(((u32)s) << 16);
}
__device__ __forceinline__ float sigmoidf_(float z) {
    return 1.0f / (1.0f + __expf(-z));
}
__device__ __forceinline__ void load_lds16(const void* g, void* l) {
    __builtin_amdgcn_global_load_lds(
        (const __attribute__((address_space(1))) void*)g,
        (__attribute__((address_space(3))) void*)l, 16, 0, 0);
}

// ---------------- weight transpose + cast: Wt[n][k] = bf16(W[k][n]) ----------------
__global__ __launch_bounds__(256) void transpose_cast_kernel(
    const float* __restrict__ W, u16* __restrict__ Wt, int K, int N)
{
    __shared__ float tile[32][33];
    const int bk = blockIdx.x * 32, bn = blockIdx.y * 32;
    const int tx = threadIdx.x, ty = threadIdx.y;   // (32,8)
    #pragma unroll
    for (int i = 0; i < 32; i += 8)
        tile[ty + i][tx] = W[(size_t)(bk + ty + i) * N + bn + tx];
    __syncthreads();
    #pragma unroll
    for (int i = 0; i < 32; i += 8)
        Wt[(size_t)(bn + ty + i) * K + bk + tx] = f2bf(tile[tx][ty + i]);
}

// ------------- GEMM mainloop (m97 structure + XOR swizzle) -------------
// A (Mxlda), Bt (Nxldb), bf16 row-major.  LDS tiles 128x64 shorts, unpadded.
__device__ __forceinline__ void gemm_mainloop(
    const u16* __restrict__ A, const int lda,
    const u16* __restrict__ Bt, const int ldb, const int K,
    const int m0, const int n0, u16* Alds, u16* Blds, f32x4 acc[4][4])
{
    const int tid  = threadIdx.x;
    const int wave = tid >> 6, lane = tid & 63;
    const int q = lane >> 4, m16 = lane & 15;
    const int wr = (wave >> 1) << 6, wc = (wave & 1) << 6;

    const f32x4 zero4 = {0.f, 0.f, 0.f, 0.f};
    #pragma unroll
    for (int i = 0; i < 4; i++)
        #pragma unroll
        for (int j = 0; j < 4; j++) acc[i][j] = zero4;

    const int sr = tid >> 3;                          // staging row 0..31
    const int sc = (((tid & 7) ^ (sr & 7)) * 8);      // swizzled source col (shorts)
    const u16* ag = &A[(size_t)(m0 + sr) * lda + sc];
    const u16* bg = &Bt[(size_t)(n0 + sr) * ldb + sc];
    u16* al = &Alds[tid * 8];         // DMA dst: lane*16 bytes (fixed)
    u16* bl = &Blds[tid * 8];

    const int xh = (m16 & 7);         // read-side XOR key (= row&7 for all frags)

    for (int k0 = 0; k0 < K; k0 += 64) {
        #pragma unroll
        for (int t = 0; t < 4; ++t) {
            load_lds16(ag + (size_t)(t * 32) * lda + k0, al + t * 2048);
            load_lds16(bg + (size_t)(t * 32) * ldb + k0, bl + t * 2048);
        }
        __syncthreads();
        #pragma unroll
        for (int s = 0; s < 2; ++s) {
            const int ch = ((s * 4 + q) ^ xh) * 8;    // swizzled chunk offset (shorts)
            bf16x8 a[4], b[4];
            #pragma unroll
            for (int i = 0; i < 4; i++)
                a[i] = *(const bf16x8*)&Alds[(wr + i * 16 + m16) * 64 + ch];
            #pragma unroll
            for (int j = 0; j < 4; j++)
                b[j] = *(const bf16x8*)&Blds[(wc + j * 16 + m16) * 64 + ch];
            #pragma unroll
            for (int i = 0; i < 4; i++)
                #pragma unroll
                for (int j = 0; j < 4; j++)
                    acc[i][j] = __builtin_amdgcn_mfma_f32_16x16x32_bf16(a[i], b[j], acc[i][j], 0, 0, 0);
        }
        __syncthreads();
    }
}

// ---------------- LN1: xn = LN(x,g1,b1) as bf16 ----------------
__global__ __launch_bounds__(256) void ln1_kernel(
    const float* __restrict__ x, const float* __restrict__ g, const float* __restrict__ b,
    u16* __restrict__ xn)
{
    const int row = blockIdx.x, tid = threadIdx.x;
    const size_t base = (size_t)row * C;
    const int c = tid * 4;
    float4 v = *(const float4*)&x[base + c];
    float s  = v.x + v.y + v.z + v.w;
    float s2 = v.x*v.x + v.y*v.y + v.z*v.z + v.w*v.w;
    #pragma unroll
    for (int off = 32; off >= 1; off >>= 1) { s += __shfl_xor(s, off); s2 += __shfl_xor(s2, off); }
    __shared__ float red[8];
    const int wave = tid >> 6, lane = tid & 63;
    if (lane == 0) { red[wave] = s; red[4 + wave] = s2; }
    __syncthreads();
    const float sum  = red[0] + red[1] + red[2] + red[3];
    const float sums = red[4] + red[5] + red[6] + red[7];
    const float mean = sum * (1.0f / C);
    const float var  = sums * (1.0f / C) - mean * mean;
    const float rstd = rsqrtf(var + 1e-5f);
    float4 gv = *(const float4*)&g[c];
    float4 bv = *(const float4*)&b[c];
    u16x4 o;
    o.x = f2bf((v.x - mean) * rstd * gv.x + bv.x);
    o.y = f2bf((v.y - mean) * rstd * gv.y + bv.y);
    o.z = f2bf((v.z - mean) * rstd * gv.z + bv.z);
    o.w = f2bf((v.w - mean) * rstd * gv.w + bv.w);
    *(u16x4*)&xn[base + c] = o;
}

// ---------------- GEMM1 + time-mix epilogue -> packed kv (dword) + r (bf16) ----------------
__global__ __launch_bounds__(256) void gemm1_kernel(
    const u16* __restrict__ xn, const u16* __restrict__ wt,
    const float* __restrict__ x,
    const float* __restrict__ tmk, const float* __restrict__ tmv, const float* __restrict__ tmr,
    u16* __restrict__ kvbuf, u16* __restrict__ rbuf)
{
    __shared__ __align__(16) u16 Alds[128 * 64];
    __shared__ __align__(16) u16 Blds[128 * 64];
    f32x4 acc[4][4];
    const int m0 = blockIdx.x * 128, n0 = blockIdx.y * 128;
    gemm_mainloop(xn, C, wt, C, C, m0, n0, Alds, Blds, acc);

    const int tid = threadIdx.x, wave = tid >> 6, lane = tid & 63;
    const int q = lane >> 4, m16 = lane & 15;
    const int wr = (wave >> 1) << 6, wc = (wave & 1) << 6;
    const int grp = n0 >> 10;                  // 0=k, 1=v, 2=r (uniform per block)
    const int cbase = (n0 & 1023) + wc;
    #pragma unroll
    for (int i = 0; i < 4; i++) {
        #pragma unroll
        for (int rg = 0; rg < 4; rg++) {
            const int row = m0 + wr + i * 16 + q * 4 + rg;
            const int t = row & (T - 1);
            const size_t rowp = (size_t)(t ? row - 1 : row) * C;   // time-mix x_prev row
            #pragma unroll
            for (int j = 0; j < 4; j++) {
                const int cc = cbase + j * 16 + m16;
                const float val = acc[i][j][rg];
                const float xp = x[rowp + cc];
                if (grp == 0) {
                    const float f = tmk[cc];
                    kvbuf[(size_t)row * 2048 + 2 * cc] = f2bf(val * f + xp * (1.0f - f));
                } else if (grp == 1) {
                    const float f = tmv[cc];
                    kvbuf[(size_t)row * 2048 + 2 * cc + 1] = f2bf(val * f + xp * (1.0f - f));
                } else {
                    const float f = tmr[cc];
                    rbuf[(size_t)row * C + cc] = f2bf(sigmoidf_(val * f + xp * (1.0f - f)));
                }
            }
        }
    }
}

// ================= WKV chunked parallel scan =================
__global__ __launch_bounds__(256) void wkv_k1(
    const u32* __restrict__ kvp, const float* __restrict__ wdec, float* __restrict__ bc)
{
    const int tid = blockIdx.x * 256 + threadIdx.x;
    const int c = tid & (C - 1), ci = tid >> 10;
    const float w = wdec[c];
    const size_t L = ((size_t)(ci >> 6) * T + (size_t)(ci & (NCH - 1)) * LCH) * C + c;
    float bb = -1e38f;
    #pragma unroll 4
    for (int t = 0; t < LCH; ++t) {
        const float k = bf2f((u16)(kvp[L + (size_t)t * C] & 0xffffu));
        const float ww = w + bb;
        const float p = fmaxf(ww, k);
        const float e1 = __expf(ww - p), e2 = __expf(k - p);
        bb = p + __logf(e1 + e2 + 1e-8f);
    }
    bc[tid] = bb;
}

__global__ __launch_bounds__(256) void wkv_p1(
    const float* __restrict__ bc, const float* __restrict__ wdec, float* __restrict__ bbin)
{
    const int gid = blockIdx.x * 256 + threadIdx.x;   // 0..8191 = b*C + c
    const int c = gid & (C - 1), b = gid >> 10;
    const float Lw = (float)LCH * wdec[c];
    float bb = -1e38f;
    #pragma unroll 8
    for (int j = 0; j < NCH; ++j) {
        const int idx = (b * NCH + j) * C + c;
        bbin[idx] = bb;
        const float a = Lw + bb;
        const float bcv = bc[idx];
        const float m = fmaxf(a, bcv);
        bb = m + __logf(__expf(a - m) + __expf(bcv - m));
    }
}

__global__ __launch_bounds__(256) void wkv_k2a(
    const u32* __restrict__ kvp, const float* __restrict__ wdec,
    const float* __restrict__ bbin, float* __restrict__ logS, float* __restrict__ Rr)
{
    const int tid = blockIdx.x * 256 + threadIdx.x;
    const int c = tid & (C - 1), ci = tid >> 10;
    const float w = wdec[c];
    const size_t L = ((size_t)(ci >> 6) * T + (size_t)(ci & (NCH - 1)) * LCH) * C + c;
    float bb = bbin[tid], ls = 0.0f, R = 0.0f;
    #pragma unroll 4
    for (int t = 0; t < LCH; ++t) {
        const u32 kv = kvp[L + (size_t)t * C];
        const float k = bf2f((u16)(kv & 0xffffu)), v = bf2f((u16)(kv >> 16));
        const float ww = w + bb;
        const float p = fmaxf(ww, k);
        const float e1 = __expf(ww - p), e2 = __expf(k - p);
        R = e1 * R + e2 * v;
        ls += ww - p;                       // log of alpha product (<=0)
        bb = p + __logf(e1 + e2 + 1e-8f);
    }
    logS[tid] = ls;
    Rr[tid] = R;
}

__global__ __launch_bounds__(256) void wkv_p2(
    const float* __restrict__ logS, const float* __restrict__ Rr, float* __restrict__ aain)
{
    const int gid = blockIdx.x * 256 + threadIdx.x;   // b*C + c
    const int c = gid & (C - 1), b = gid >> 10;
    float a = 0.0f;
    #pragma unroll 8
    for (int j = 0; j < NCH; ++j) {
        const int idx = (b * NCH + j) * C + c;
        aain[idx] = a;
        a = __expf(logS[idx]) * a + Rr[idx];
    }
}

__global__ __launch_bounds__(256) void wkv_k2c(
    const u32* __restrict__ kvp, const u16* __restrict__ rbuf, const float* __restrict__ x,
    const float* __restrict__ wdec, const float* __restrict__ ufirst,
    const float* __restrict__ bbin, const float* __restrict__ aain,
    float* __restrict__ x2, float* __restrict__ state)
{
    const int tid = blockIdx.x * 256 + threadIdx.x;
    const int c = tid & (C - 1), ci = tid >> 10;
    const int b = ci >> 6, j = ci & (NCH - 1);
    const float w = wdec[c], u = ufirst[c];
    float aa = aain[tid], bb = bbin[tid];
    const size_t L = ((size_t)b * T + (size_t)j * LCH) * C + c;
    #pragma unroll 4
    for (int t = 0; t < LCH; ++t) {
        const size_t idx = L + (size_t)t * C;
        const u32 kv = kvp[idx];
        const float k = bf2f((u16)(kv & 0xffffu)), v = bf2f((u16)(kv >> 16));
        const float r = bf2f(rbuf[idx]), xv = x[idx];
        float ww = u + k;
        float p  = fmaxf(bb, ww);
        float e1 = __expf(bb - p), e2 = __expf(ww - p);
        const float y = (e1 * aa + e2 * v) / (e1 + e2 + 1e-8f);
        x2[idx] = xv + r * y;
        ww = w + bb;
        p  = fmaxf(ww, k);
        e1 = __expf(ww - p); e2 = __expf(k - p);
        aa = e1 * aa + e2 * v;
        bb = p + __logf(e1 + e2 + 1e-8f);
    }
    if (j == NCH - 1) {
        state[2 * (b * C + c)]     = aa;
        state[2 * (b * C + c) + 1] = bb;
    }
}

// ---------------- LN2 + rr + xp_s snapshot ----------------
__global__ __launch_bounds__(256) void ln2_kernel(
    const float* __restrict__ x2, const float* __restrict__ g, const float* __restrict__ b,
    const float* __restrict__ cmr, u16* __restrict__ xn, u16* __restrict__ rr,
    u16* __restrict__ xps)
{
    const int row = blockIdx.x, tid = threadIdx.x;
    const size_t base = (size_t)row * C;
    const int t = row & (T - 1);
    const size_t basep = (size_t)(row - t + (t ? t - 1 : T - 1)) * C;   // cm xp row (wraps)
    const int c = tid * 4;
    float4 v = *(const float4*)&x2[base + c];
    float s  = v.x + v.y + v.z + v.w;
    float s2 = v.x*v.x + v.y*v.y + v.z*v.z + v.w*v.w;
    #pragma unroll
    for (int off = 32; off >= 1; off >>= 1) { s += __shfl_xor(s, off); s2 += __shfl_xor(s2, off); }
    __shared__ float red[8];
    const int wave = tid >> 6, lane = tid & 63;
    if (lane == 0) { red[wave] = s; red[4 + wave] = s2; }
    __syncthreads();
    const float sum  = red[0] + red[1] + red[2] + red[3];
    const float sums = red[4] + red[5] + red[6] + red[7];
    const float mean = sum * (1.0f / C);
    const float var  = sums * (1.0f / C) - mean * mean;
    const float rstd = rsqrtf(var + 1e-5f);
    float4 gv = *(const float4*)&g[c];
    float4 bv = *(const float4*)&b[c];
    float4 fv = *(const float4*)&cmr[c];
    float4 xp = *(const float4*)&x2[basep + c];
    float xn0 = (v.x - mean) * rstd * gv.x + bv.x;
    float xn1 = (v.y - mean) * rstd * gv.y + bv.y;
    float xn2 = (v.z - mean) * rstd * gv.z + bv.z;
    float xn3 = (v.w - mean) * rstd * gv.w + bv.w;
    u16x4 o; o.x = f2bf(xn0); o.y = f2bf(xn1); o.z = f2bf(xn2); o.w = f2bf(xn3);
    *(u16x4*)&xn[base + c] = o;
    u16x4 p4; p4.x = f2bf(xp.x); p4.y = f2bf(xp.y); p4.z = f2bf(xp.z); p4.w = f2bf(xp.w);
    *(u16x4*)&xps[base + c] = p4;
    u16x4 r4;
    r4.x = f2bf(sigmoidf_(xn0 * fv.x + xp.x * (1.0f - fv.x)));
    r4.y = f2bf(sigmoidf_(xn1 * fv.y + xp.y * (1.0f - fv.y)));
    r4.z = f2bf(sigmoidf_(xn2 * fv.z + xp.z * (1.0f - fv.z)));
    r4.w = f2bf(sigmoidf_(xn3 * fv.w + xp.w * (1.0f - fv.w)));
    *(u16x4*)&rr[base + c] = r4;
}

// ---------------- GEMM2 (one 2048-col half) + cm-mix + relu^2 -> h_half (bf16) ----------------
__global__ __launch_bounds__(256) void gemm2_kernel(
    const u16* __restrict__ xn, const u16* __restrict__ wt,   // wt pre-offset to half
    const u16* __restrict__ xps, const float* __restrict__ cmk,
    u16* __restrict__ hbuf, const int nbase)
{
    __shared__ __align__(16) u16 Alds[128 * 64];
    __shared__ __align__(16) u16 Blds[128 * 64];
    f32x4 acc[4][4];
    const int m0 = blockIdx.x * 128, n0 = blockIdx.y * 128;
    gemm_mainloop(xn, C, wt, C, C, m0, n0, Alds, Blds, acc);

    const int tid = threadIdx.x, wave = tid >> 6, lane = tid & 63;
    const int q = lane >> 4, m16 = lane & 15;
    const int wr = (wave >> 1) << 6, wc = (wave & 1) << 6;
    #pragma unroll
    for (int i = 0; i < 4; i++) {
        #pragma unroll
        for (int rg = 0; rg < 4; rg++) {
            const int row = m0 + wr + i * 16 + q * 4 + rg;
            #pragma unroll
            for (int j = 0; j < 4; j++) {
                const int nloc = n0 + wc + j * 16 + m16;         // 0..2047 within half
                const int cc = (nbase + nloc) & (C - 1);
                const float f = cmk[cc];
                const float xp = bf2f(xps[(size_t)row * C + cc]);
                const float kk = acc[i][j][rg] * f + xp * (1.0f - f);
                const float h = fmaxf(kk, 0.0f);
                hbuf[(size_t)row * 2048 + nloc] = f2bf(h * h);
            }
        }
    }
}

// ---------------- GEMM3 (K=2048 half) + residual epilogue, accumulates into out ----------------
__global__ __launch_bounds__(256) void gemm3_kernel(
    const u16* __restrict__ hbuf, const u16* __restrict__ wt,  // wt pre-offset to half
    const u16* __restrict__ rr, float* __restrict__ out)
{
    __shared__ __align__(16) u16 Alds[128 * 64];
    __shared__ __align__(16) u16 Blds[128 * 64];
    f32x4 acc[4][4];
    const int m0 = blockIdx.x * 128, n0 = blockIdx.y * 128;
    gemm_mainloop(hbuf, 2048, wt, 4096, 2048, m0, n0, Alds, Blds, acc);

    const int tid = threadIdx.x, wave = tid >> 6, lane = tid & 63;
    const int q = lane >> 4, m16 = lane & 15;
    const int wr = (wave >> 1) << 6, wc = (wave & 1) << 6;
    #pragma unroll
    for (int i = 0; i < 4; i++) {
        #pragma unroll
        for (int rg = 0; rg < 4; rg++) {
            const int row = m0 + wr + i * 16 + q * 4 + rg;
            #pragma unroll
            for (int j = 0; j < 4; j++) {
                const int cc = n0 + wc + j * 16 + m16;
                const size_t idx = (size_t)row * C + cc;
                const float base = out[idx];   // pass0: x2; pass1: partial result
                out[idx] = base + bf2f(rr[idx]) * acc[i][j][rg];
            }
        }
    }
}

// ---------------- workspace layout (byte offsets), total 176 MB ----------------
#define OFF_WT_CM  0            //  8 MB  (4096 x 1024 bf16)
#define OFF_WT_CP  8388608      //  8 MB  (1024 x 4096 bf16)
#define OFF_XN     16777216     // 32 MB  (M x C bf16; LN1 then LN2)
#define OFF_KV     50331648     // 64 MB  (M x C packed (k,v) bf16 pairs)
#define OFF_H      OFF_KV       // 64 MB  (M x 2048 bf16 half; overlays kv, dead after wkv)
#define OFF_RB     117440512    // 32 MB  (bf16; reused as rr after wkv)
#define OFF_WT_TM  150994944    //  6 MB  (3072 x 1024 bf16; dead after gemm1)
// wkv scratch overlays the wt_tm/xps extent during the scan (dead then):
#define OFF_BC     150994944    // 2 MB
#define OFF_BBIN   153092096    // 2 MB
#define OFF_LOGS   155189248    // 2 MB
#define OFF_RCH    157286400    // 2 MB
#define OFF_AAIN   159383552    // 2 MB
#define OFF_XPS    150994944    // 32 MB (bf16 shifted x2; born at ln2, after wkv)

extern "C" void kernel_launch(void* const* d_in, const int* in_sizes, int n_in,
                              void* d_out, int out_size, void* d_ws, size_t ws_size,
                              hipStream_t stream) {
    const float* x          = (const float*)d_in[0];
    const float* time_decay = (const float*)d_in[1];
    const float* time_first = (const float*)d_in[2];
    const float* W_tm       = (const float*)d_in[3];
    const float* g1         = (const float*)d_in[4];
    const float* b1         = (const float*)d_in[5];
    const float* tmk        = (const float*)d_in[6];
    const float* tmv        = (const float*)d_in[7];
    const float* tmr        = (const float*)d_in[8];
    const float* W_cm       = (const float*)d_in[9];
    const float* W_cp       = (const float*)d_in[10];
    const float* g2         = (const float*)d_in[11];
    const float* b2         = (const float*)d_in[12];
    const float* cmk        = (const float*)d_in[13];
    const float* cmr        = (const float*)d_in[14];
    float* out = (float*)d_out;

    char* ws = (char*)d_ws;
    u16*   wt_cm = (u16*)(ws + OFF_WT_CM);
    u16*   wt_cp = (u16*)(ws + OFF_WT_CP);
    u16*   xn    = (u16*)(ws + OFF_XN);
    u16*   kvbuf = (u16*)(ws + OFF_KV);
    u16*   hbuf  = (u16*)(ws + OFF_H);
    u16*   rbuf  = (u16*)(ws + OFF_RB);   // rr reuses this after wkv
    u16*   wt_tm = (u16*)(ws + OFF_WT_TM);
    u16*   xps   = (u16*)(ws + OFF_XPS);
    float* bc    = (float*)(ws + OFF_BC);
    float* bbin  = (float*)(ws + OFF_BBIN);
    float* logS  = (float*)(ws + OFF_LOGS);
    float* Rch   = (float*)(ws + OFF_RCH);
    float* aain  = (float*)(ws + OFF_AAIN);
    float* x2    = out;                    // residual stream lives in d_out

    // 1. weights -> bf16 B^T
    transpose_cast_kernel<<<dim3(1024/32, 3072/32), dim3(32, 8), 0, stream>>>(W_tm, wt_tm, 1024, 3072);
    transpose_cast_kernel<<<dim3(1024/32, 4096/32), dim3(32, 8), 0, stream>>>(W_cm, wt_cm, 1024, 4096);
    transpose_cast_kernel<<<dim3(4096/32, 1024/32), dim3(32, 8), 0, stream>>>(W_cp, wt_cp, 4096, 1024);
    // 2. LN1
    ln1_kernel<<<M, 256, 0, stream>>>(x, g1, b1, xn);
    // 3. GEMM1 + time-mix
    gemm1_kernel<<<dim3(M/128, 3072/128), 256, 0, stream>>>(xn, wt_tm, x, tmk, tmv, tmr,
                                                            kvbuf, rbuf);
    // 4. WKV chunked parallel scan (x2 -> d_out body, state -> d_out tail)
    {
        const u32* kvp = (const u32*)kvbuf;
        wkv_k1 <<<WKV_THREADS/256, 256, 0, stream>>>(kvp, time_decay, bc);
        wkv_p1 <<<(Bb*C)/256, 256, 0, stream>>>(bc, time_decay, bbin);
        wkv_k2a<<<WKV_THREADS/256, 256, 0, stream>>>(kvp, time_decay, bbin, logS, Rch);
        wkv_p2 <<<(Bb*C)/256, 256, 0, stream>>>(logS, Rch, aain);
        wkv_k2c<<<WKV_THREADS/256, 256, 0, stream>>>(kvp, rbuf, x, time_decay, time_first,
                                                     bbin, aain, x2, out + (size_t)M * C);
    }
    // 5. LN2 + rr + xp snapshot
    ln2_kernel<<<M, 256, 0, stream>>>(x2, g2, b2, cmr, xn, rbuf, xps);
    // 6+7. channel-mix GEMMs in two hidden-halves (h_half overlays dead kv)
    for (int half = 0; half < 2; ++half) {
        const int nbase = half * 2048;
        gemm2_kernel<<<dim3(M/128, 2048/128), 256, 0, stream>>>(
            xn, wt_cm + (size_t)nbase * C, xps, cmk, hbuf, nbase);
        gemm3_kernel<<<dim3(M/128, 1024/128), 256, 0, stream>>>(
            hbuf, wt_cp + nbase, rbuf, out);
    }
}